// Round 4
// baseline (384.405 us; speedup 1.0000x reference)
//
#include <hip/hip_runtime.h>
#include <hip/hip_bf16.h>
#include <cstdint>
#include <cstddef>

// MultiHeadAttention: B=4, T=2048, D=1024, H=16, dh=64, fp32 in/out.
// Pipeline: cvt(x->Xb), cvt(qkv_w->Wb in d_out scratch) ;
//           qkv_gemm (128^2 2-phase, verified) -> Q*c1, K, Vt ;
//           attn (flash, transposed-MFMA, LDS-staged K/V, setprio) -> ctx ;
//           cvt(out_w->Ob) ; out_gemm -> fp32 out.
//
// R2 post-mortem: 256^2 8-phase port regressed (grid tails: 384 and 128
// blocks; 1-resident). Reverted to the verified 128^2 GEMMs.
// R3 adds: (a) qkv V-epilogue LDS-transpose -> t-contiguous 16B stores
// (old path: 8B/lane at 4KB stride = 4x DRAM write amplification);
// (b) attn setprio(1) around MFMA clusters (T5, attn-proven +4-7%);
// (c) hoisted zero C-operand for S-MFMA init.

#define SEQ 2048
#define DM 1024

typedef __attribute__((ext_vector_type(8))) short bf16x8;
typedef __attribute__((ext_vector_type(4))) short bf16x4;
typedef __attribute__((ext_vector_type(4))) float f32x4;

static __device__ __forceinline__ short f2bf(float f) {
  union { float f; uint32_t u; } v; v.f = f;
  uint32_t r = v.u + 0x7fffu + ((v.u >> 16) & 1u);
  return (short)(r >> 16);
}

typedef const __attribute__((address_space(1))) unsigned int* gas_ptr;
typedef __attribute__((address_space(3))) unsigned int* las_ptr;
static __device__ __forceinline__ void gl2lds16(const void* g, void* l) {
  __builtin_amdgcn_global_load_lds((gas_ptr)g, (las_ptr)l, 16, 0, 0);
}

// truncating pack of two fp32 into bf16 pair: one v_perm_b32
static __device__ __forceinline__ unsigned permhi(float a_odd, float a_even) {
  union { float f; unsigned u; } x, y; x.f = a_odd; y.f = a_even;
  return __builtin_amdgcn_perm(x.u, y.u, 0x07060302u);
}
static __device__ __forceinline__ bf16x8 pack8t(const float* e) {
  union { bf16x8 v; unsigned u[4]; } r;
  r.u[0] = permhi(e[1], e[0]);
  r.u[1] = permhi(e[3], e[2]);
  r.u[2] = permhi(e[5], e[4]);
  r.u[3] = permhi(e[7], e[6]);
  return r.v;
}

// attn swizzle: chunk c (16B) of tile row r stored at LDS chunk r*8 + (c ^ swz(r))
static __device__ __forceinline__ int swz(int r) {
  return (r & 3) | (((r >> 3) & 1) << 2);
}

// ---------------- Kernel 0: fp32 -> bf16 convert ----------------
__global__ __launch_bounds__(256)
void cvt_bf16(const float* __restrict__ src, short* __restrict__ dst) {
  int i = blockIdx.x * 256 + threadIdx.x;
  float4 v = ((const float4*)src)[i];
  bf16x4 p = { f2bf(v.x), f2bf(v.y), f2bf(v.z), f2bf(v.w) };
  ((bf16x4*)dst)[i] = p;
}

// ---------------- Kernel 1: QKV projection GEMM (all-bf16 staging) ----------------
__global__ __launch_bounds__(256, 2)
void qkv_gemm(const short* __restrict__ Xb, const short* __restrict__ Wb,
              const float* __restrict__ bias,
              short* __restrict__ Q, short* __restrict__ K,
              short* __restrict__ Vt) {
  // unified 32 KB: As = smem[0..8191], Bs = smem[8192..16383] (shorts);
  // reused whole as a 128 x 128-short transpose buffer in the V epilogue.
  __shared__ short smem[2 * 128 * 64];
  short* As = smem;
  short* Bs = smem + 128 * 64;
  const int tid  = threadIdx.x;
  const int m0   = blockIdx.x * 128;
  const int n0   = blockIdx.y * 128;
  const int lane = tid & 63;
  const int w    = tid >> 6;
  const int wm   = (w >> 1) * 64, wn = (w & 1) * 64;
  const int l15  = lane & 15, quad = lane >> 4;
  const int arow = w * 8 + (lane >> 3), acol = (lane & 7) << 3;

  f32x4 acc[4][4];
  for (int i = 0; i < 4; i++)
    for (int j = 0; j < 4; j++) acc[i][j] = (f32x4)0.0f;

  for (int k0 = 0; k0 < DM; k0 += 64) {
#pragma unroll
    for (int p = 0; p < 4; p++) {
      gl2lds16(&Xb[(size_t)(m0 + p * 32 + arow) * DM + k0 + acol], &As[(p * 32 + w * 8) * 64]);
      gl2lds16(&Wb[(size_t)(n0 + p * 32 + arow) * DM + k0 + acol], &Bs[(p * 32 + w * 8) * 64]);
    }
    __syncthreads();
#pragma unroll
    for (int ks = 0; ks < 64; ks += 32) {
      bf16x8 af[4], bfr[4];
      for (int i = 0; i < 4; i++)
        af[i] = *(const bf16x8*)&As[(wm + i * 16 + l15) * 64 + ks + quad * 8];
      for (int j = 0; j < 4; j++)
        bfr[j] = *(const bf16x8*)&Bs[(wn + j * 16 + l15) * 64 + ks + quad * 8];
      for (int i = 0; i < 4; i++)
        for (int j = 0; j < 4; j++)
          acc[i][j] = __builtin_amdgcn_mfma_f32_16x16x32_bf16(af[i], bfr[j], acc[i][j], 0, 0, 0);
    }
    __syncthreads();
  }

  const float C1 = 0.18033688011112042f;   // 0.125 * log2(e), folded into Q
  const int qkv = n0 >> 10;
  if (qkv == 2) {
    // ---- V epilogue: LDS transpose -> t-contiguous coalesced stores ----
    // smem as [f_local 0..127] rows of 128 shorts (t_local), 16B chunks
    // XOR-swizzled by (f & 7) to spread banks.
#pragma unroll
    for (int i = 0; i < 4; i++) {
      const int t0 = wm + i * 16 + quad * 4;
      const int hc = t0 >> 2;          // 8B half-chunk index 0..31
      const int ch = hc >> 1;          // 16B chunk 0..15
#pragma unroll
      for (int j = 0; j < 4; j++) {
        const int f_l = wn + j * 16 + l15;
        const float bv = bias[n0 + f_l];
        bf16x4 pk = { f2bf(acc[i][j][0] + bv), f2bf(acc[i][j][1] + bv),
                      f2bf(acc[i][j][2] + bv), f2bf(acc[i][j][3] + bv) };
        int addr = f_l * 256 + ((ch ^ (f_l & 7)) << 4) + ((hc & 1) << 3);
        *(bf16x4*)((char*)smem + addr) = pk;
      }
    }
    __syncthreads();
    // store phase: 256 threads, row = f_local (2 threads/row), 128B per thread
    const int row = tid >> 1, seg = tid & 1;
    const int fg  = (n0 & 1023) + row;
    const int hh  = fg >> 6, dd = fg & 63;
    const size_t gb = ((size_t)((m0 >> 11) * 16 + hh) * 64 + dd) * SEQ
                    + (m0 & 2047) + seg * 64;
#pragma unroll
    for (int k = 0; k < 8; k++) {
      const int ci = seg * 8 + k;
      bf16x8 val = *(const bf16x8*)((const char*)smem + row * 256 + ((ci ^ (row & 7)) << 4));
      *(bf16x8*)&Vt[gb + k * 8] = val;
    }
  } else {
    for (int i = 0; i < 4; i++) {
      const int m = m0 + wm + i * 16 + quad * 4;
      const int bb = m >> 11, t = m & 2047;
      for (int j = 0; j < 4; j++) {
        const int f  = n0 + wn + j * 16 + l15;
        const int fi = f & 1023;
        const int h  = fi >> 6, d = fi & 63;
        const float bv = bias[f];
        short* dst = (qkv == 0) ? Q : K;
        const float sc = (qkv == 0) ? C1 : 1.0f;
        size_t base = ((size_t)(bb * 16 + h) * SEQ + t) * 64 + d;
        for (int r = 0; r < 4; r++)
          dst[base + (size_t)r * 64] = f2bf((acc[i][j][r] + bv) * sc);
      }
    }
  }
}

// ---------------- Kernel 2: flash attention (LDS-staged K/V) ----------------
// grid (T/128, B*H); 4 waves/block; each wave owns 32 q-rows (2 m-tiles).
// S^T = mfma(A=K(perm), B=Q*c1); p = 2^S -> v_perm trunc pack -> P^T B-frags;
// O^T = mfma(A=V^T, B=P^T); row-sums via ones-row MFMA.
// R3: setprio(1) around MFMA clusters (T5); hoisted zero C for S init.
__global__ __launch_bounds__(256, 4)
void attn(const short* __restrict__ Q, const short* __restrict__ K,
          const short* __restrict__ Vt, short* __restrict__ ctx) {
  __shared__ short Ks[2][64 * 64];   // 8 KB per buffer, swizzled chunks
  __shared__ short Vs[2][64 * 64];
  const int tid  = threadIdx.x;
  const int w    = tid >> 6, lane = tid & 63;
  const int l15  = lane & 15, quad = lane >> 4;
  const int bh   = blockIdx.y;
  const int qr   = blockIdx.x * 128 + w * 32;
  const short* Kb = &K[(size_t)bh * SEQ * 64];
  const short* Vb = &Vt[(size_t)bh * 64 * SEQ];

  const int kperm = (l15 >> 2) * 8 + (l15 & 3);   // + tau*4 -> permuted K row

  // DMA chunk mapping (2 chunks per tile per thread per matrix)
  int dr[2], dc[2];
#pragma unroll
  for (int p = 0; p < 2; p++) {
    int ci = p * 256 + w * 64 + lane;
    dr[p] = ci >> 3;
    dc[p] = (ci & 7) ^ swz(ci >> 3);
  }
  // incrementing DMA source pointers, positioned at tile 1
  const short* kp[2];
  const short* vp[2];
#pragma unroll
  for (int p = 0; p < 2; p++) {
    kp[p] = &Kb[(size_t)(64 + dr[p]) * 64 + dc[p] * 8];
    vp[p] = &Vb[(size_t)dr[p] * SEQ + 64 + dc[p] * 8];
  }

  // cached LDS byte-offsets for both buffers
  int koff[2][2][2][2];   // [buf][blk][tau][ks]
  int voff[2][4][2];      // [buf][dt][blk]
#pragma unroll
  for (int blk = 0; blk < 2; blk++)
#pragma unroll
    for (int tau = 0; tau < 2; tau++)
#pragma unroll
      for (int ks = 0; ks < 2; ks++) {
        int R = blk * 32 + kperm + tau * 4;
        int c = (ks * 4 + quad) ^ swz(R);
        int off = (R * 8 + c) * 16;
        koff[0][blk][tau][ks] = off;
        koff[1][blk][tau][ks] = off + 8192;
      }
#pragma unroll
  for (int dt = 0; dt < 4; dt++)
#pragma unroll
    for (int blk = 0; blk < 2; blk++) {
      int R = dt * 16 + l15;
      int c = (blk * 4 + quad) ^ swz(R);
      int off = (R * 8 + c) * 16;
      voff[0][dt][blk] = off;
      voff[1][dt][blk] = off + 8192;
    }
  const char* KsB = (const char*)&Ks[0][0];
  const char* VsB = (const char*)&Vs[0][0];

  bf16x8 qf[2][2];
#pragma unroll
  for (int mt = 0; mt < 2; mt++)
#pragma unroll
    for (int ks = 0; ks < 2; ks++)
      qf[mt][ks] = *(const bf16x8*)&Q[(size_t)bh * SEQ * 64 + (size_t)(qr + mt * 16 + l15) * 64 + ks * 32 + quad * 8];

  f32x4 O[2][4];
#pragma unroll
  for (int mt = 0; mt < 2; mt++)
    for (int dt = 0; dt < 4; dt++) O[mt][dt] = (f32x4)0.0f;
  f32x4 psA[2];
  psA[0] = (f32x4)0.0f; psA[1] = (f32x4)0.0f;
  const short one_bf = (short)0x3F80;
  const bf16x8 ones = { one_bf, one_bf, one_bf, one_bf, one_bf, one_bf, one_bf, one_bf };
  // hoisted zero C-operand for S-MFMA init
  f32x4 fz = (f32x4)0.0f;

  // prologue: DMA tile 0 into buffer 0
#pragma unroll
  for (int p = 0; p < 2; p++) {
    gl2lds16(&Kb[(size_t)dr[p] * 64 + dc[p] * 8],  &Ks[0][(p * 256 + w * 64) * 8]);
    gl2lds16(&Vb[(size_t)dr[p] * SEQ + dc[p] * 8], &Vs[0][(p * 256 + w * 64) * 8]);
  }
  __syncthreads();

  for (int k0 = 0; k0 < SEQ; k0 += 128) {
#pragma unroll
    for (int half = 0; half < 2; half++) {
      // prefetch next tile into the other buffer
      const bool doPf = (half == 0) || (k0 + 128 < SEQ);
      if (doPf) {
#pragma unroll
        for (int p = 0; p < 2; p++) {
          gl2lds16(kp[p], &Ks[half ^ 1][(p * 256 + w * 64) * 8]);
          gl2lds16(vp[p], &Vs[half ^ 1][(p * 256 + w * 64) * 8]);
        }
      }
#pragma unroll
      for (int p = 0; p < 2; p++) { kp[p] += 64 * 64; vp[p] += 64; }

      // K fragments (cached offsets)
      bf16x8 kf[2][2][2];
#pragma unroll
      for (int blk = 0; blk < 2; blk++)
#pragma unroll
        for (int tau = 0; tau < 2; tau++)
#pragma unroll
          for (int ks = 0; ks < 2; ks++)
            kf[blk][tau][ks] = *(const bf16x8*)(KsB + koff[half][blk][tau][ks]);

      // S^T = K Q^T
      f32x4 S[2][2][2];
      __builtin_amdgcn_s_setprio(1);
#pragma unroll
      for (int mt = 0; mt < 2; mt++)
#pragma unroll
        for (int blk = 0; blk < 2; blk++) {
          f32x4 S0, S1;
          S0 = __builtin_amdgcn_mfma_f32_16x16x32_bf16(kf[blk][0][0], qf[mt][0], fz, 0, 0, 0);
          S1 = __builtin_amdgcn_mfma_f32_16x16x32_bf16(kf[blk][1][0], qf[mt][0], fz, 0, 0, 0);
          S0 = __builtin_amdgcn_mfma_f32_16x16x32_bf16(kf[blk][0][1], qf[mt][1], S0, 0, 0, 0);
          S1 = __builtin_amdgcn_mfma_f32_16x16x32_bf16(kf[blk][1][1], qf[mt][1], S1, 0, 0, 0);
          S[mt][blk][0] = S0; S[mt][blk][1] = S1;
        }
      __builtin_amdgcn_s_setprio(0);

      // V^T fragments (cached offsets)
      bf16x8 vf[4][2];
#pragma unroll
      for (int dt = 0; dt < 4; dt++)
#pragma unroll
        for (int blk = 0; blk < 2; blk++)
          vf[dt][blk] = *(const bf16x8*)(VsB + voff[half][dt][blk]);

      // p = 2^S ; truncating v_perm pack into PV B-frags
      bf16x8 pp[2][2];
#pragma unroll
      for (int mt = 0; mt < 2; mt++)
#pragma unroll
        for (int blk = 0; blk < 2; blk++) {
          float e[8];
#pragma unroll
          for (int r = 0; r < 4; r++) {
            e[r]     = exp2f(S[mt][blk][0][r]);
            e[4 + r] = exp2f(S[mt][blk][1][r]);
          }
          pp[mt][blk] = pack8t(e);
        }

      // O^T += V^T P^T ; psum += ones·P^T
      __builtin_amdgcn_s_setprio(1);
#pragma unroll
      for (int blk = 0; blk < 2; blk++) {
#pragma unroll
        for (int dt = 0; dt < 4; dt++) {
          O[0][dt] = __builtin_amdgcn_mfma_f32_16x16x32_bf16(vf[dt][blk], pp[0][blk], O[0][dt], 0, 0, 0);
          O[1][dt] = __builtin_amdgcn_mfma_f32_16x16x32_bf16(vf[dt][blk], pp[1][blk], O[1][dt], 0, 0, 0);
        }
        psA[0] = __builtin_amdgcn_mfma_f32_16x16x32_bf16(ones, pp[0][blk], psA[0], 0, 0, 0);
        psA[1] = __builtin_amdgcn_mfma_f32_16x16x32_bf16(ones, pp[1][blk], psA[1], 0, 0, 0);
      }
      __builtin_amdgcn_s_setprio(0);

      __syncthreads();
    }
  }

  const int bb = bh >> 4, h = bh & 15;
#pragma unroll
  for (int mt = 0; mt < 2; mt++) {
    float rinv = 1.0f / psA[mt][0];
    const int t = qr + mt * 16 + l15;
#pragma unroll
    for (int dt = 0; dt < 4; dt++) {
      bf16x4 ov = { f2bf(O[mt][dt][0] * rinv), f2bf(O[mt][dt][1] * rinv),
                    f2bf(O[mt][dt][2] * rinv), f2bf(O[mt][dt][3] * rinv) };
      *(bf16x4*)&ctx[(size_t)(bb * SEQ + t) * DM + h * 64 + dt * 16 + quad * 4] = ov;
    }
  }
}

// ---------------- Kernel 3: output projection GEMM ----------------
__global__ __launch_bounds__(256, 2)
void out_gemm(const short* __restrict__ Cx, const short* __restrict__ Ob,
              const float* __restrict__ bias, float* __restrict__ Y) {
  __shared__ short As[128][64];
  __shared__ short Bs[128][64];
  const int tid  = threadIdx.x;
  const int m0   = blockIdx.x * 128;
  const int n0   = blockIdx.y * 128;
  const int lane = tid & 63;
  const int w    = tid >> 6;
  const int wm   = (w >> 1) * 64, wn = (w & 1) * 64;
  const int l15  = lane & 15, quad = lane >> 4;
  const int arow = w * 8 + (lane >> 3), acol = (lane & 7) << 3;

  f32x4 acc[4][4];
  for (int i = 0; i < 4; i++)
    for (int j = 0; j < 4; j++) acc[i][j] = (f32x4)0.0f;

  for (int k0 = 0; k0 < DM; k0 += 64) {
#pragma unroll
    for (int p = 0; p < 4; p++) {
      gl2lds16(&Cx[(size_t)(m0 + p * 32 + arow) * DM + k0 + acol], &As[p * 32 + w * 8][0]);
      gl2lds16(&Ob[(size_t)(n0 + p * 32 + arow) * DM + k0 + acol], &Bs[p * 32 + w * 8][0]);
    }
    __syncthreads();
#pragma unroll
    for (int ks = 0; ks < 64; ks += 32) {
      bf16x8 af[4], bfr[4];
      for (int i = 0; i < 4; i++)
        af[i] = *(const bf16x8*)&As[wm + i * 16 + l15][ks + quad * 8];
      for (int j = 0; j < 4; j++)
        bfr[j] = *(const bf16x8*)&Bs[wn + j * 16 + l15][ks + quad * 8];
      for (int i = 0; i < 4; i++)
        for (int j = 0; j < 4; j++)
          acc[i][j] = __builtin_amdgcn_mfma_f32_16x16x32_bf16(af[i], bfr[j], acc[i][j], 0, 0, 0);
    }
    __syncthreads();
  }

  for (int i = 0; i < 4; i++) {
    const int m = m0 + wm + i * 16 + quad * 4;
    for (int j = 0; j < 4; j++) {
      const int n = n0 + wn + j * 16 + l15;
      const float bv = bias[n];
      for (int r = 0; r < 4; r++)
        Y[(size_t)(m + r) * DM + n] = acc[i][j][r] + bv;
    }
  }
}

extern "C" void kernel_launch(void* const* d_in, const int* in_sizes, int n_in,
                              void* d_out, int out_size, void* d_ws, size_t ws_size,
                              hipStream_t stream) {
  const float* x     = (const float*)d_in[0];
  const float* qkv_w = (const float*)d_in[1];
  const float* qkv_b = (const float*)d_in[2];
  const float* out_w = (const float*)d_in[3];
  const float* out_b = (const float*)d_in[4];
  float* out = (float*)d_out;

  const size_t NBH = (size_t)4 * 16 * SEQ * 64;   // 8,388,608 elements
  short* Q   = (short*)d_ws;
  short* K   = Q + NBH;
  short* Vt  = K + NBH;      // after attn, reused as Ob (bf16 out_w)
  short* ctx = Vt + NBH;     // before attn, holds Xb (bf16 x)
  short* Xb  = ctx;
  short* Ob  = Vt;
  short* Wb  = (short*)d_out; // bf16 qkv_w scratch in d_out (dead until out_gemm)

  cvt_bf16<<<dim3(8192), 256, 0, stream>>>(x, Xb);
  cvt_bf16<<<dim3(3072), 256, 0, stream>>>(qkv_w, Wb);
  qkv_gemm<<<dim3(64, 24), 256, 0, stream>>>(Xb, Wb, qkv_b, Q, K, Vt);
  attn<<<dim3(SEQ / 128, 64), 256, 0, stream>>>(Q, K, Vt, ctx);
  cvt_bf16<<<dim3(1024), 256, 0, stream>>>(out_w, Ob);
  out_gemm<<<dim3(64, 8), 256, 0, stream>>>(ctx, Ob, out_b, out);
}

// Round 5
// 286.071 us; speedup vs baseline: 1.3437x; 1.3437x over previous
//
#include <hip/hip_runtime.h>
#include <hip/hip_bf16.h>
#include <cstdint>
#include <cstddef>

// MultiHeadAttention: B=4, T=2048, D=1024, H=16, dh=64, fp32 in/out.
// Pipeline: cvt(x->Xb), cvt(qkv_w->Wb in d_out scratch) ;
//           qkv_gemm (all-bf16) -> Q*c1, K, Vt ;
//           attn (flash, transposed-MFMA, LDS-staged K/V, exp2 no-shift,
//                 ones-MFMA row sums, cached LDS offsets) -> ctx ;
//           cvt(out_w->Ob) ; out_gemm -> fp32 out.
//
// R4 post-mortem: R3's bundle (attn setprio + fz hoist + qkv V-transpose
// epilogue) coincided with attn 109.6->203.6us and an unexplained 5x HBM
// traffic blow-up (WRITE 19.4->537MB in the attn window). No derivable
// mechanism from the diff -> full byte-for-byte revert to the R1 source
// (measured 287.6us / 284.7us on two separate healthy sessions).
// This run re-fingerprints: attn ~109.6us, FETCH ~141MB, WRITE ~19.4MB.

#define SEQ 2048
#define DM 1024

typedef __attribute__((ext_vector_type(8))) short bf16x8;
typedef __attribute__((ext_vector_type(4))) short bf16x4;
typedef __attribute__((ext_vector_type(4))) float f32x4;

static __device__ __forceinline__ short f2bf(float f) {
  union { float f; uint32_t u; } v; v.f = f;
  uint32_t r = v.u + 0x7fffu + ((v.u >> 16) & 1u);
  return (short)(r >> 16);
}

typedef const __attribute__((address_space(1))) unsigned int* gas_ptr;
typedef __attribute__((address_space(3))) unsigned int* las_ptr;
static __device__ __forceinline__ void gl2lds16(const void* g, void* l) {
  __builtin_amdgcn_global_load_lds((gas_ptr)g, (las_ptr)l, 16, 0, 0);
}

// truncating pack of two fp32 into bf16 pair: one v_perm_b32
static __device__ __forceinline__ unsigned permhi(float a_odd, float a_even) {
  union { float f; unsigned u; } x, y; x.f = a_odd; y.f = a_even;
  return __builtin_amdgcn_perm(x.u, y.u, 0x07060302u);
}
static __device__ __forceinline__ bf16x8 pack8t(const float* e) {
  union { bf16x8 v; unsigned u[4]; } r;
  r.u[0] = permhi(e[1], e[0]);
  r.u[1] = permhi(e[3], e[2]);
  r.u[2] = permhi(e[5], e[4]);
  r.u[3] = permhi(e[7], e[6]);
  return r.v;
}

// swizzle: chunk c (16B) of tile row r stored at LDS chunk r*8 + (c ^ swz(r))
static __device__ __forceinline__ int swz(int r) {
  return (r & 3) | (((r >> 3) & 1) << 2);
}

// ---------------- Kernel 0: fp32 -> bf16 convert ----------------
__global__ __launch_bounds__(256)
void cvt_bf16(const float* __restrict__ src, short* __restrict__ dst) {
  int i = blockIdx.x * 256 + threadIdx.x;
  float4 v = ((const float4*)src)[i];
  bf16x4 p = { f2bf(v.x), f2bf(v.y), f2bf(v.z), f2bf(v.w) };
  ((bf16x4*)dst)[i] = p;
}

// ---------------- Kernel 1: QKV projection GEMM (all-bf16 staging) ----------------
__global__ __launch_bounds__(256, 2)
void qkv_gemm(const short* __restrict__ Xb, const short* __restrict__ Wb,
              const float* __restrict__ bias,
              short* __restrict__ Q, short* __restrict__ K,
              short* __restrict__ Vt) {
  __shared__ short As[128][64];
  __shared__ short Bs[128][64];
  const int tid  = threadIdx.x;
  const int m0   = blockIdx.x * 128;
  const int n0   = blockIdx.y * 128;
  const int lane = tid & 63;
  const int w    = tid >> 6;
  const int wm   = (w >> 1) * 64, wn = (w & 1) * 64;
  const int l15  = lane & 15, quad = lane >> 4;
  const int arow = w * 8 + (lane >> 3), acol = (lane & 7) << 3;

  f32x4 acc[4][4];
  for (int i = 0; i < 4; i++)
    for (int j = 0; j < 4; j++) acc[i][j] = (f32x4)0.0f;

  for (int k0 = 0; k0 < DM; k0 += 64) {
#pragma unroll
    for (int p = 0; p < 4; p++) {
      gl2lds16(&Xb[(size_t)(m0 + p * 32 + arow) * DM + k0 + acol], &As[p * 32 + w * 8][0]);
      gl2lds16(&Wb[(size_t)(n0 + p * 32 + arow) * DM + k0 + acol], &Bs[p * 32 + w * 8][0]);
    }
    __syncthreads();
#pragma unroll
    for (int ks = 0; ks < 64; ks += 32) {
      bf16x8 af[4], bfr[4];
      for (int i = 0; i < 4; i++)
        af[i] = *(const bf16x8*)&As[wm + i * 16 + l15][ks + quad * 8];
      for (int j = 0; j < 4; j++)
        bfr[j] = *(const bf16x8*)&Bs[wn + j * 16 + l15][ks + quad * 8];
      for (int i = 0; i < 4; i++)
        for (int j = 0; j < 4; j++)
          acc[i][j] = __builtin_amdgcn_mfma_f32_16x16x32_bf16(af[i], bfr[j], acc[i][j], 0, 0, 0);
    }
    __syncthreads();
  }

  const float C1 = 0.18033688011112042f;   // 0.125 * log2(e), folded into Q
  const int qkv = n0 >> 10;
  for (int i = 0; i < 4; i++) {
    const int m = m0 + wm + i * 16 + quad * 4;
    const int bb = m >> 11, t = m & 2047;
    for (int j = 0; j < 4; j++) {
      const int f  = n0 + wn + j * 16 + l15;
      const int fi = f & 1023;
      const int h  = fi >> 6, d = fi & 63;
      const float bv = bias[f];
      if (qkv == 2) {
        bf16x4 pk = { f2bf(acc[i][j][0] + bv), f2bf(acc[i][j][1] + bv),
                      f2bf(acc[i][j][2] + bv), f2bf(acc[i][j][3] + bv) };
        *(bf16x4*)&Vt[((size_t)(bb * 16 + h) * 64 + d) * SEQ + t] = pk;
      } else {
        short* dst = (qkv == 0) ? Q : K;
        const float sc = (qkv == 0) ? C1 : 1.0f;
        size_t base = ((size_t)(bb * 16 + h) * SEQ + t) * 64 + d;
        for (int r = 0; r < 4; r++)
          dst[base + (size_t)r * 64] = f2bf((acc[i][j][r] + bv) * sc);
      }
    }
  }
}

// ---------------- Kernel 2: flash attention (LDS-staged K/V) ----------------
// grid (T/128, B*H); 4 waves/block; each wave owns 32 q-rows (2 m-tiles).
// S^T = mfma(A=K(perm), B=Q*c1); p = 2^S -> v_perm trunc pack -> P^T B-frags;
// O^T = mfma(A=V^T, B=P^T); row-sums via ones-row MFMA.
// launch_bounds(256,4): 4 blocks/CU resident to saturate the exp pipe
// (VGPR 72 fits under the 128 cap; LDS 4x32KB = 128KB).
__global__ __launch_bounds__(256, 4)
void attn(const short* __restrict__ Q, const short* __restrict__ K,
          const short* __restrict__ Vt, short* __restrict__ ctx) {
  __shared__ short Ks[2][64 * 64];   // 8 KB per buffer, swizzled chunks
  __shared__ short Vs[2][64 * 64];
  const int tid  = threadIdx.x;
  const int w    = tid >> 6, lane = tid & 63;
  const int l15  = lane & 15, quad = lane >> 4;
  const int bh   = blockIdx.y;
  const int qr   = blockIdx.x * 128 + w * 32;
  const short* Kb = &K[(size_t)bh * SEQ * 64];
  const short* Vb = &Vt[(size_t)bh * 64 * SEQ];

  const int kperm = (l15 >> 2) * 8 + (l15 & 3);   // + tau*4 -> permuted K row

  // DMA chunk mapping (2 chunks per tile per thread per matrix)
  int dr[2], dc[2];
#pragma unroll
  for (int p = 0; p < 2; p++) {
    int ci = p * 256 + w * 64 + lane;
    dr[p] = ci >> 3;
    dc[p] = (ci & 7) ^ swz(ci >> 3);
  }
  // incrementing DMA source pointers, positioned at tile 1
  const short* kp[2];
  const short* vp[2];
#pragma unroll
  for (int p = 0; p < 2; p++) {
    kp[p] = &Kb[(size_t)(64 + dr[p]) * 64 + dc[p] * 8];
    vp[p] = &Vb[(size_t)dr[p] * SEQ + 64 + dc[p] * 8];
  }

  // cached LDS byte-offsets for both buffers
  int koff[2][2][2][2];   // [buf][blk][tau][ks]
  int voff[2][4][2];      // [buf][dt][blk]
#pragma unroll
  for (int blk = 0; blk < 2; blk++)
#pragma unroll
    for (int tau = 0; tau < 2; tau++)
#pragma unroll
      for (int ks = 0; ks < 2; ks++) {
        int R = blk * 32 + kperm + tau * 4;
        int c = (ks * 4 + quad) ^ swz(R);
        int off = (R * 8 + c) * 16;
        koff[0][blk][tau][ks] = off;
        koff[1][blk][tau][ks] = off + 8192;
      }
#pragma unroll
  for (int dt = 0; dt < 4; dt++)
#pragma unroll
    for (int blk = 0; blk < 2; blk++) {
      int R = dt * 16 + l15;
      int c = (blk * 4 + quad) ^ swz(R);
      int off = (R * 8 + c) * 16;
      voff[0][dt][blk] = off;
      voff[1][dt][blk] = off + 8192;
    }
  const char* KsB = (const char*)&Ks[0][0];
  const char* VsB = (const char*)&Vs[0][0];

  bf16x8 qf[2][2];
#pragma unroll
  for (int mt = 0; mt < 2; mt++)
#pragma unroll
    for (int ks = 0; ks < 2; ks++)
      qf[mt][ks] = *(const bf16x8*)&Q[(size_t)bh * SEQ * 64 + (size_t)(qr + mt * 16 + l15) * 64 + ks * 32 + quad * 8];

  f32x4 O[2][4];
#pragma unroll
  for (int mt = 0; mt < 2; mt++)
    for (int dt = 0; dt < 4; dt++) O[mt][dt] = (f32x4)0.0f;
  f32x4 psA[2];
  psA[0] = (f32x4)0.0f; psA[1] = (f32x4)0.0f;
  const short one_bf = (short)0x3F80;
  const bf16x8 ones = { one_bf, one_bf, one_bf, one_bf, one_bf, one_bf, one_bf, one_bf };

  // prologue: DMA tile 0 into buffer 0
#pragma unroll
  for (int p = 0; p < 2; p++) {
    gl2lds16(&Kb[(size_t)dr[p] * 64 + dc[p] * 8],  &Ks[0][(p * 256 + w * 64) * 8]);
    gl2lds16(&Vb[(size_t)dr[p] * SEQ + dc[p] * 8], &Vs[0][(p * 256 + w * 64) * 8]);
  }
  __syncthreads();

  for (int k0 = 0; k0 < SEQ; k0 += 128) {
#pragma unroll
    for (int half = 0; half < 2; half++) {
      // prefetch next tile into the other buffer
      const bool doPf = (half == 0) || (k0 + 128 < SEQ);
      if (doPf) {
#pragma unroll
        for (int p = 0; p < 2; p++) {
          gl2lds16(kp[p], &Ks[half ^ 1][(p * 256 + w * 64) * 8]);
          gl2lds16(vp[p], &Vs[half ^ 1][(p * 256 + w * 64) * 8]);
        }
      }
#pragma unroll
      for (int p = 0; p < 2; p++) { kp[p] += 64 * 64; vp[p] += 64; }

      // K fragments (cached offsets)
      bf16x8 kf[2][2][2];
#pragma unroll
      for (int blk = 0; blk < 2; blk++)
#pragma unroll
        for (int tau = 0; tau < 2; tau++)
#pragma unroll
          for (int ks = 0; ks < 2; ks++)
            kf[blk][tau][ks] = *(const bf16x8*)(KsB + koff[half][blk][tau][ks]);

      // S^T = K Q^T
      f32x4 S[2][2][2];
#pragma unroll
      for (int mt = 0; mt < 2; mt++)
#pragma unroll
        for (int blk = 0; blk < 2; blk++) {
          f32x4 S0 = (f32x4)0.0f, S1 = (f32x4)0.0f;
#pragma unroll
          for (int ks = 0; ks < 2; ks++) {
            S0 = __builtin_amdgcn_mfma_f32_16x16x32_bf16(kf[blk][0][ks], qf[mt][ks], S0, 0, 0, 0);
            S1 = __builtin_amdgcn_mfma_f32_16x16x32_bf16(kf[blk][1][ks], qf[mt][ks], S1, 0, 0, 0);
          }
          S[mt][blk][0] = S0; S[mt][blk][1] = S1;
        }

      // V^T fragments (cached offsets)
      bf16x8 vf[4][2];
#pragma unroll
      for (int dt = 0; dt < 4; dt++)
#pragma unroll
        for (int blk = 0; blk < 2; blk++)
          vf[dt][blk] = *(const bf16x8*)(VsB + voff[half][dt][blk]);

      // p = 2^S ; truncating v_perm pack into PV B-frags
      bf16x8 pp[2][2];
#pragma unroll
      for (int mt = 0; mt < 2; mt++)
#pragma unroll
        for (int blk = 0; blk < 2; blk++) {
          float e[8];
#pragma unroll
          for (int r = 0; r < 4; r++) {
            e[r]     = exp2f(S[mt][blk][0][r]);
            e[4 + r] = exp2f(S[mt][blk][1][r]);
          }
          pp[mt][blk] = pack8t(e);
        }

      // O^T += V^T P^T ; psum += ones·P^T
#pragma unroll
      for (int blk = 0; blk < 2; blk++) {
#pragma unroll
        for (int dt = 0; dt < 4; dt++) {
          O[0][dt] = __builtin_amdgcn_mfma_f32_16x16x32_bf16(vf[dt][blk], pp[0][blk], O[0][dt], 0, 0, 0);
          O[1][dt] = __builtin_amdgcn_mfma_f32_16x16x32_bf16(vf[dt][blk], pp[1][blk], O[1][dt], 0, 0, 0);
        }
        psA[0] = __builtin_amdgcn_mfma_f32_16x16x32_bf16(ones, pp[0][blk], psA[0], 0, 0, 0);
        psA[1] = __builtin_amdgcn_mfma_f32_16x16x32_bf16(ones, pp[1][blk], psA[1], 0, 0, 0);
      }

      __syncthreads();
    }
  }

  const int bb = bh >> 4, h = bh & 15;
#pragma unroll
  for (int mt = 0; mt < 2; mt++) {
    float rinv = 1.0f / psA[mt][0];
    const int t = qr + mt * 16 + l15;
#pragma unroll
    for (int dt = 0; dt < 4; dt++) {
      bf16x4 ov = { f2bf(O[mt][dt][0] * rinv), f2bf(O[mt][dt][1] * rinv),
                    f2bf(O[mt][dt][2] * rinv), f2bf(O[mt][dt][3] * rinv) };
      *(bf16x4*)&ctx[(size_t)(bb * SEQ + t) * DM + h * 64 + dt * 16 + quad * 4] = ov;
    }
  }
}

// ---------------- Kernel 3: output projection GEMM ----------------
__global__ __launch_bounds__(256, 2)
void out_gemm(const short* __restrict__ Cx, const short* __restrict__ Ob,
              const float* __restrict__ bias, float* __restrict__ Y) {
  __shared__ short As[128][64];
  __shared__ short Bs[128][64];
  const int tid  = threadIdx.x;
  const int m0   = blockIdx.x * 128;
  const int n0   = blockIdx.y * 128;
  const int lane = tid & 63;
  const int w    = tid >> 6;
  const int wm   = (w >> 1) * 64, wn = (w & 1) * 64;
  const int l15  = lane & 15, quad = lane >> 4;
  const int arow = w * 8 + (lane >> 3), acol = (lane & 7) << 3;

  f32x4 acc[4][4];
  for (int i = 0; i < 4; i++)
    for (int j = 0; j < 4; j++) acc[i][j] = (f32x4)0.0f;

  for (int k0 = 0; k0 < DM; k0 += 64) {
#pragma unroll
    for (int p = 0; p < 4; p++) {
      gl2lds16(&Cx[(size_t)(m0 + p * 32 + arow) * DM + k0 + acol], &As[p * 32 + w * 8][0]);
      gl2lds16(&Ob[(size_t)(n0 + p * 32 + arow) * DM + k0 + acol], &Bs[p * 32 + w * 8][0]);
    }
    __syncthreads();
#pragma unroll
    for (int ks = 0; ks < 64; ks += 32) {
      bf16x8 af[4], bfr[4];
      for (int i = 0; i < 4; i++)
        af[i] = *(const bf16x8*)&As[wm + i * 16 + l15][ks + quad * 8];
      for (int j = 0; j < 4; j++)
        bfr[j] = *(const bf16x8*)&Bs[wn + j * 16 + l15][ks + quad * 8];
      for (int i = 0; i < 4; i++)
        for (int j = 0; j < 4; j++)
          acc[i][j] = __builtin_amdgcn_mfma_f32_16x16x32_bf16(af[i], bfr[j], acc[i][j], 0, 0, 0);
    }
    __syncthreads();
  }

  for (int i = 0; i < 4; i++) {
    const int m = m0 + wm + i * 16 + quad * 4;
    for (int j = 0; j < 4; j++) {
      const int n = n0 + wn + j * 16 + l15;
      const float bv = bias[n];
      for (int r = 0; r < 4; r++)
        Y[(size_t)(m + r) * DM + n] = acc[i][j][r] + bv;
    }
  }
}

extern "C" void kernel_launch(void* const* d_in, const int* in_sizes, int n_in,
                              void* d_out, int out_size, void* d_ws, size_t ws_size,
                              hipStream_t stream) {
  const float* x     = (const float*)d_in[0];
  const float* qkv_w = (const float*)d_in[1];
  const float* qkv_b = (const float*)d_in[2];
  const float* out_w = (const float*)d_in[3];
  const float* out_b = (const float*)d_in[4];
  float* out = (float*)d_out;

  const size_t NBH = (size_t)4 * 16 * SEQ * 64;   // 8,388,608 elements
  short* Q   = (short*)d_ws;
  short* K   = Q + NBH;
  short* Vt  = K + NBH;      // after attn, reused as Ob (bf16 out_w)
  short* ctx = Vt + NBH;     // before attn, holds Xb (bf16 x)
  short* Xb  = ctx;
  short* Ob  = Vt;
  short* Wb  = (short*)d_out; // bf16 qkv_w scratch in d_out (dead until out_gemm)

  cvt_bf16<<<dim3(8192), 256, 0, stream>>>(x, Xb);
  cvt_bf16<<<dim3(3072), 256, 0, stream>>>(qkv_w, Wb);
  qkv_gemm<<<dim3(64, 24), 256, 0, stream>>>(Xb, Wb, qkv_b, Q, K, Vt);
  attn<<<dim3(SEQ / 128, 64), 256, 0, stream>>>(Q, K, Vt, ctx);
  cvt_bf16<<<dim3(1024), 256, 0, stream>>>(out_w, Ob);
  out_gemm<<<dim3(64, 8), 256, 0, stream>>>(ctx, Ob, out_b, out);
}

// Round 6
// 278.992 us; speedup vs baseline: 1.3778x; 1.0254x over previous
//
#include <hip/hip_runtime.h>
#include <hip/hip_bf16.h>
#include <cstdint>
#include <cstddef>

// MultiHeadAttention: B=4, T=2048, D=1024, H=16, dh=64, fp32 in/out.
// Pipeline: cvt(x->Xb), cvt(qkv_w->Wb in d_out scratch) ;
//           qkv_gemm -> Q*c1, K, Vt ; attn -> ctx ;
//           cvt(out_w->Ob) ; out_gemm -> fp32 out.
//
// R5 confirmed baseline (286us; attn 109.6us fingerprint). R6 changes ONE
// mechanism, GEMMs only (attn byte-identical): the old loop was
// stage->sync->compute->sync = ZERO prefetch, full global->LDS latency
// exposed every K-step (16x). New loop: LDS double-buffer, issue stage(t+1)
// BEFORE compute(t), counted s_waitcnt vmcnt(8) (t+1's loads in flight
// across compute + barrier), raw s_barrier + sched_barrier(0). Plus the
// proven 8-chunk XOR swizzle (pre-swizzled gl2lds source + swizzled read
// offsets, same pattern as attn staging) so the de-stalled ds_reads don't
// hit the 16-way row-stride bank conflict. Accumulation order unchanged
// -> bit-identical results.

#define SEQ 2048
#define DM 1024

typedef __attribute__((ext_vector_type(8))) short bf16x8;
typedef __attribute__((ext_vector_type(4))) short bf16x4;
typedef __attribute__((ext_vector_type(4))) float f32x4;

static __device__ __forceinline__ short f2bf(float f) {
  union { float f; uint32_t u; } v; v.f = f;
  uint32_t r = v.u + 0x7fffu + ((v.u >> 16) & 1u);
  return (short)(r >> 16);
}

typedef const __attribute__((address_space(1))) unsigned int* gas_ptr;
typedef __attribute__((address_space(3))) unsigned int* las_ptr;
static __device__ __forceinline__ void gl2lds16(const void* g, void* l) {
  __builtin_amdgcn_global_load_lds((gas_ptr)g, (las_ptr)l, 16, 0, 0);
}

// truncating pack of two fp32 into bf16 pair: one v_perm_b32
static __device__ __forceinline__ unsigned permhi(float a_odd, float a_even) {
  union { float f; unsigned u; } x, y; x.f = a_odd; y.f = a_even;
  return __builtin_amdgcn_perm(x.u, y.u, 0x07060302u);
}
static __device__ __forceinline__ bf16x8 pack8t(const float* e) {
  union { bf16x8 v; unsigned u[4]; } r;
  r.u[0] = permhi(e[1], e[0]);
  r.u[1] = permhi(e[3], e[2]);
  r.u[2] = permhi(e[5], e[4]);
  r.u[3] = permhi(e[7], e[6]);
  return r.v;
}

// swizzle: chunk c (16B) of tile row r stored at LDS chunk r*8 + (c ^ swz(r))
static __device__ __forceinline__ int swz(int r) {
  return (r & 3) | (((r >> 3) & 1) << 2);
}

// ---------------- Kernel 0: fp32 -> bf16 convert ----------------
__global__ __launch_bounds__(256)
void cvt_bf16(const float* __restrict__ src, short* __restrict__ dst) {
  int i = blockIdx.x * 256 + threadIdx.x;
  float4 v = ((const float4*)src)[i];
  bf16x4 p = { f2bf(v.x), f2bf(v.y), f2bf(v.z), f2bf(v.w) };
  ((bf16x4*)dst)[i] = p;
}

// ---------------- Kernel 1: QKV projection GEMM (prefetch + counted vmcnt) ----------------
__global__ __launch_bounds__(256, 2)
void qkv_gemm(const short* __restrict__ Xb, const short* __restrict__ Wb,
              const float* __restrict__ bias,
              short* __restrict__ Q, short* __restrict__ K,
              short* __restrict__ Vt) {
  __shared__ short As[2][128 * 64];
  __shared__ short Bs[2][128 * 64];
  const int tid  = threadIdx.x;
  const int m0   = blockIdx.x * 128;
  const int n0   = blockIdx.y * 128;
  const int lane = tid & 63;
  const int w    = tid >> 6;
  const int wm   = (w >> 1) * 64, wn = (w & 1) * 64;
  const int l15  = lane & 15, quad = lane >> 4;

  // staging map (swizzled source, linear LDS dest)
  int g_row[4], g_col[4];
#pragma unroll
  for (int p = 0; p < 4; p++) {
    int r = p * 32 + w * 8 + (lane >> 3);
    g_row[p] = r;
    g_col[p] = ((lane & 7) ^ swz(r)) << 3;
  }
  // cached swizzled read byte-offsets
  int aoff[4][2], boff[4][2];
#pragma unroll
  for (int i = 0; i < 4; i++)
#pragma unroll
    for (int ks = 0; ks < 2; ks++) {
      int Ra = wm + i * 16 + l15;
      aoff[i][ks] = Ra * 128 + (((ks * 4 + quad) ^ swz(Ra)) << 4);
      int Rb = wn + i * 16 + l15;
      boff[i][ks] = Rb * 128 + (((ks * 4 + quad) ^ swz(Rb)) << 4);
    }

  f32x4 acc[4][4];
  for (int i = 0; i < 4; i++)
    for (int j = 0; j < 4; j++) acc[i][j] = (f32x4)0.0f;

  // prologue: stage K-tile 0 into buffer 0
#pragma unroll
  for (int p = 0; p < 4; p++) {
    gl2lds16(&Xb[(size_t)(m0 + g_row[p]) * DM + g_col[p]], &As[0][(p * 32 + w * 8) * 64]);
    gl2lds16(&Wb[(size_t)(n0 + g_row[p]) * DM + g_col[p]], &Bs[0][(p * 32 + w * 8) * 64]);
  }

  for (int t = 0; t < 16; t++) {
    const int cur = t & 1;
    if (t + 1 < 16) {
      const int kk = (t + 1) * 64;
#pragma unroll
      for (int p = 0; p < 4; p++) {
        gl2lds16(&Xb[(size_t)(m0 + g_row[p]) * DM + kk + g_col[p]], &As[cur ^ 1][(p * 32 + w * 8) * 64]);
        gl2lds16(&Wb[(size_t)(n0 + g_row[p]) * DM + kk + g_col[p]], &Bs[cur ^ 1][(p * 32 + w * 8) * 64]);
      }
      asm volatile("s_waitcnt vmcnt(8)" ::: "memory");   // tile t landed; t+1 in flight
    } else {
      asm volatile("s_waitcnt vmcnt(0)" ::: "memory");
    }
    __builtin_amdgcn_s_barrier();
    __builtin_amdgcn_sched_barrier(0);

    const char* Ab = (const char*)&As[cur][0];
    const char* Bb = (const char*)&Bs[cur][0];
#pragma unroll
    for (int ks = 0; ks < 2; ks++) {
      bf16x8 af[4], bfr[4];
      for (int i = 0; i < 4; i++) af[i]  = *(const bf16x8*)(Ab + aoff[i][ks]);
      for (int j = 0; j < 4; j++) bfr[j] = *(const bf16x8*)(Bb + boff[j][ks]);
      for (int i = 0; i < 4; i++)
        for (int j = 0; j < 4; j++)
          acc[i][j] = __builtin_amdgcn_mfma_f32_16x16x32_bf16(af[i], bfr[j], acc[i][j], 0, 0, 0);
    }
    __builtin_amdgcn_sched_barrier(0);
    __builtin_amdgcn_s_barrier();     // readers of buf done before next stage overwrites
    __builtin_amdgcn_sched_barrier(0);
  }

  const float C1 = 0.18033688011112042f;   // 0.125 * log2(e), folded into Q
  const int qkv = n0 >> 10;
  for (int i = 0; i < 4; i++) {
    const int m = m0 + wm + i * 16 + quad * 4;
    const int bb = m >> 11, t = m & 2047;
    for (int j = 0; j < 4; j++) {
      const int f  = n0 + wn + j * 16 + l15;
      const int fi = f & 1023;
      const int h  = fi >> 6, d = fi & 63;
      const float bv = bias[f];
      if (qkv == 2) {
        bf16x4 pk = { f2bf(acc[i][j][0] + bv), f2bf(acc[i][j][1] + bv),
                      f2bf(acc[i][j][2] + bv), f2bf(acc[i][j][3] + bv) };
        *(bf16x4*)&Vt[((size_t)(bb * 16 + h) * 64 + d) * SEQ + t] = pk;
      } else {
        short* dst = (qkv == 0) ? Q : K;
        const float sc = (qkv == 0) ? C1 : 1.0f;
        size_t base = ((size_t)(bb * 16 + h) * SEQ + t) * 64 + d;
        for (int r = 0; r < 4; r++)
          dst[base + (size_t)r * 64] = f2bf((acc[i][j][r] + bv) * sc);
      }
    }
  }
}

// ---------------- Kernel 2: flash attention (LDS-staged K/V) ----------------
// grid (T/128, B*H); 4 waves/block; each wave owns 32 q-rows (2 m-tiles).
// S^T = mfma(A=K(perm), B=Q*c1); p = 2^S -> v_perm trunc pack -> P^T B-frags;
// O^T = mfma(A=V^T, B=P^T); row-sums via ones-row MFMA.
// launch_bounds(256,4): 4 blocks/CU resident to saturate the exp pipe
// (VGPR 72 fits under the 128 cap; LDS 4x32KB = 128KB).
__global__ __launch_bounds__(256, 4)
void attn(const short* __restrict__ Q, const short* __restrict__ K,
          const short* __restrict__ Vt, short* __restrict__ ctx) {
  __shared__ short Ks[2][64 * 64];   // 8 KB per buffer, swizzled chunks
  __shared__ short Vs[2][64 * 64];
  const int tid  = threadIdx.x;
  const int w    = tid >> 6, lane = tid & 63;
  const int l15  = lane & 15, quad = lane >> 4;
  const int bh   = blockIdx.y;
  const int qr   = blockIdx.x * 128 + w * 32;
  const short* Kb = &K[(size_t)bh * SEQ * 64];
  const short* Vb = &Vt[(size_t)bh * 64 * SEQ];

  const int kperm = (l15 >> 2) * 8 + (l15 & 3);   // + tau*4 -> permuted K row

  // DMA chunk mapping (2 chunks per tile per thread per matrix)
  int dr[2], dc[2];
#pragma unroll
  for (int p = 0; p < 2; p++) {
    int ci = p * 256 + w * 64 + lane;
    dr[p] = ci >> 3;
    dc[p] = (ci & 7) ^ swz(ci >> 3);
  }
  // incrementing DMA source pointers, positioned at tile 1
  const short* kp[2];
  const short* vp[2];
#pragma unroll
  for (int p = 0; p < 2; p++) {
    kp[p] = &Kb[(size_t)(64 + dr[p]) * 64 + dc[p] * 8];
    vp[p] = &Vb[(size_t)dr[p] * SEQ + 64 + dc[p] * 8];
  }

  // cached LDS byte-offsets for both buffers
  int koff[2][2][2][2];   // [buf][blk][tau][ks]
  int voff[2][4][2];      // [buf][dt][blk]
#pragma unroll
  for (int blk = 0; blk < 2; blk++)
#pragma unroll
    for (int tau = 0; tau < 2; tau++)
#pragma unroll
      for (int ks = 0; ks < 2; ks++) {
        int R = blk * 32 + kperm + tau * 4;
        int c = (ks * 4 + quad) ^ swz(R);
        int off = (R * 8 + c) * 16;
        koff[0][blk][tau][ks] = off;
        koff[1][blk][tau][ks] = off + 8192;
      }
#pragma unroll
  for (int dt = 0; dt < 4; dt++)
#pragma unroll
    for (int blk = 0; blk < 2; blk++) {
      int R = dt * 16 + l15;
      int c = (blk * 4 + quad) ^ swz(R);
      int off = (R * 8 + c) * 16;
      voff[0][dt][blk] = off;
      voff[1][dt][blk] = off + 8192;
    }
  const char* KsB = (const char*)&Ks[0][0];
  const char* VsB = (const char*)&Vs[0][0];

  bf16x8 qf[2][2];
#pragma unroll
  for (int mt = 0; mt < 2; mt++)
#pragma unroll
    for (int ks = 0; ks < 2; ks++)
      qf[mt][ks] = *(const bf16x8*)&Q[(size_t)bh * SEQ * 64 + (size_t)(qr + mt * 16 + l15) * 64 + ks * 32 + quad * 8];

  f32x4 O[2][4];
#pragma unroll
  for (int mt = 0; mt < 2; mt++)
    for (int dt = 0; dt < 4; dt++) O[mt][dt] = (f32x4)0.0f;
  f32x4 psA[2];
  psA[0] = (f32x4)0.0f; psA[1] = (f32x4)0.0f;
  const short one_bf = (short)0x3F80;
  const bf16x8 ones = { one_bf, one_bf, one_bf, one_bf, one_bf, one_bf, one_bf, one_bf };

  // prologue: DMA tile 0 into buffer 0
#pragma unroll
  for (int p = 0; p < 2; p++) {
    gl2lds16(&Kb[(size_t)dr[p] * 64 + dc[p] * 8],  &Ks[0][(p * 256 + w * 64) * 8]);
    gl2lds16(&Vb[(size_t)dr[p] * SEQ + dc[p] * 8], &Vs[0][(p * 256 + w * 64) * 8]);
  }
  __syncthreads();

  for (int k0 = 0; k0 < SEQ; k0 += 128) {
#pragma unroll
    for (int half = 0; half < 2; half++) {
      // prefetch next tile into the other buffer
      const bool doPf = (half == 0) || (k0 + 128 < SEQ);
      if (doPf) {
#pragma unroll
        for (int p = 0; p < 2; p++) {
          gl2lds16(kp[p], &Ks[half ^ 1][(p * 256 + w * 64) * 8]);
          gl2lds16(vp[p], &Vs[half ^ 1][(p * 256 + w * 64) * 8]);
        }
      }
#pragma unroll
      for (int p = 0; p < 2; p++) { kp[p] += 64 * 64; vp[p] += 64; }

      // K fragments (cached offsets)
      bf16x8 kf[2][2][2];
#pragma unroll
      for (int blk = 0; blk < 2; blk++)
#pragma unroll
        for (int tau = 0; tau < 2; tau++)
#pragma unroll
          for (int ks = 0; ks < 2; ks++)
            kf[blk][tau][ks] = *(const bf16x8*)(KsB + koff[half][blk][tau][ks]);

      // S^T = K Q^T
      f32x4 S[2][2][2];
#pragma unroll
      for (int mt = 0; mt < 2; mt++)
#pragma unroll
        for (int blk = 0; blk < 2; blk++) {
          f32x4 S0 = (f32x4)0.0f, S1 = (f32x4)0.0f;
#pragma unroll
          for (int ks = 0; ks < 2; ks++) {
            S0 = __builtin_amdgcn_mfma_f32_16x16x32_bf16(kf[blk][0][ks], qf[mt][ks], S0, 0, 0, 0);
            S1 = __builtin_amdgcn_mfma_f32_16x16x32_bf16(kf[blk][1][ks], qf[mt][ks], S1, 0, 0, 0);
          }
          S[mt][blk][0] = S0; S[mt][blk][1] = S1;
        }

      // V^T fragments (cached offsets)
      bf16x8 vf[4][2];
#pragma unroll
      for (int dt = 0; dt < 4; dt++)
#pragma unroll
        for (int blk = 0; blk < 2; blk++)
          vf[dt][blk] = *(const bf16x8*)(VsB + voff[half][dt][blk]);

      // p = 2^S ; truncating v_perm pack into PV B-frags
      bf16x8 pp[2][2];
#pragma unroll
      for (int mt = 0; mt < 2; mt++)
#pragma unroll
        for (int blk = 0; blk < 2; blk++) {
          float e[8];
#pragma unroll
          for (int r = 0; r < 4; r++) {
            e[r]     = exp2f(S[mt][blk][0][r]);
            e[4 + r] = exp2f(S[mt][blk][1][r]);
          }
          pp[mt][blk] = pack8t(e);
        }

      // O^T += V^T P^T ; psum += ones·P^T
#pragma unroll
      for (int blk = 0; blk < 2; blk++) {
#pragma unroll
        for (int dt = 0; dt < 4; dt++) {
          O[0][dt] = __builtin_amdgcn_mfma_f32_16x16x32_bf16(vf[dt][blk], pp[0][blk], O[0][dt], 0, 0, 0);
          O[1][dt] = __builtin_amdgcn_mfma_f32_16x16x32_bf16(vf[dt][blk], pp[1][blk], O[1][dt], 0, 0, 0);
        }
        psA[0] = __builtin_amdgcn_mfma_f32_16x16x32_bf16(ones, pp[0][blk], psA[0], 0, 0, 0);
        psA[1] = __builtin_amdgcn_mfma_f32_16x16x32_bf16(ones, pp[1][blk], psA[1], 0, 0, 0);
      }

      __syncthreads();
    }
  }

  const int bb = bh >> 4, h = bh & 15;
#pragma unroll
  for (int mt = 0; mt < 2; mt++) {
    float rinv = 1.0f / psA[mt][0];
    const int t = qr + mt * 16 + l15;
#pragma unroll
    for (int dt = 0; dt < 4; dt++) {
      bf16x4 ov = { f2bf(O[mt][dt][0] * rinv), f2bf(O[mt][dt][1] * rinv),
                    f2bf(O[mt][dt][2] * rinv), f2bf(O[mt][dt][3] * rinv) };
      *(bf16x4*)&ctx[(size_t)(bb * SEQ + t) * DM + h * 64 + dt * 16 + quad * 4] = ov;
    }
  }
}

// ---------------- Kernel 3: output projection GEMM (prefetch + counted vmcnt) ----------------
__global__ __launch_bounds__(256, 2)
void out_gemm(const short* __restrict__ Cx, const short* __restrict__ Ob,
              const float* __restrict__ bias, float* __restrict__ Y) {
  __shared__ short As[2][128 * 64];
  __shared__ short Bs[2][128 * 64];
  const int tid  = threadIdx.x;
  const int m0   = blockIdx.x * 128;
  const int n0   = blockIdx.y * 128;
  const int lane = tid & 63;
  const int w    = tid >> 6;
  const int wm   = (w >> 1) * 64, wn = (w & 1) * 64;
  const int l15  = lane & 15, quad = lane >> 4;

  int g_row[4], g_col[4];
#pragma unroll
  for (int p = 0; p < 4; p++) {
    int r = p * 32 + w * 8 + (lane >> 3);
    g_row[p] = r;
    g_col[p] = ((lane & 7) ^ swz(r)) << 3;
  }
  int aoff[4][2], boff[4][2];
#pragma unroll
  for (int i = 0; i < 4; i++)
#pragma unroll
    for (int ks = 0; ks < 2; ks++) {
      int Ra = wm + i * 16 + l15;
      aoff[i][ks] = Ra * 128 + (((ks * 4 + quad) ^ swz(Ra)) << 4);
      int Rb = wn + i * 16 + l15;
      boff[i][ks] = Rb * 128 + (((ks * 4 + quad) ^ swz(Rb)) << 4);
    }

  f32x4 acc[4][4];
  for (int i = 0; i < 4; i++)
    for (int j = 0; j < 4; j++) acc[i][j] = (f32x4)0.0f;

#pragma unroll
  for (int p = 0; p < 4; p++) {
    gl2lds16(&Cx[(size_t)(m0 + g_row[p]) * DM + g_col[p]], &As[0][(p * 32 + w * 8) * 64]);
    gl2lds16(&Ob[(size_t)(n0 + g_row[p]) * DM + g_col[p]], &Bs[0][(p * 32 + w * 8) * 64]);
  }

  for (int t = 0; t < 16; t++) {
    const int cur = t & 1;
    if (t + 1 < 16) {
      const int kk = (t + 1) * 64;
#pragma unroll
      for (int p = 0; p < 4; p++) {
        gl2lds16(&Cx[(size_t)(m0 + g_row[p]) * DM + kk + g_col[p]], &As[cur ^ 1][(p * 32 + w * 8) * 64]);
        gl2lds16(&Ob[(size_t)(n0 + g_row[p]) * DM + kk + g_col[p]], &Bs[cur ^ 1][(p * 32 + w * 8) * 64]);
      }
      asm volatile("s_waitcnt vmcnt(8)" ::: "memory");
    } else {
      asm volatile("s_waitcnt vmcnt(0)" ::: "memory");
    }
    __builtin_amdgcn_s_barrier();
    __builtin_amdgcn_sched_barrier(0);

    const char* Ab = (const char*)&As[cur][0];
    const char* Bb = (const char*)&Bs[cur][0];
#pragma unroll
    for (int ks = 0; ks < 2; ks++) {
      bf16x8 af[4], bfr[4];
      for (int i = 0; i < 4; i++) af[i]  = *(const bf16x8*)(Ab + aoff[i][ks]);
      for (int j = 0; j < 4; j++) bfr[j] = *(const bf16x8*)(Bb + boff[j][ks]);
      for (int i = 0; i < 4; i++)
        for (int j = 0; j < 4; j++)
          acc[i][j] = __builtin_amdgcn_mfma_f32_16x16x32_bf16(af[i], bfr[j], acc[i][j], 0, 0, 0);
    }
    __builtin_amdgcn_sched_barrier(0);
    __builtin_amdgcn_s_barrier();
    __builtin_amdgcn_sched_barrier(0);
  }

  for (int i = 0; i < 4; i++) {
    const int m = m0 + wm + i * 16 + quad * 4;
    for (int j = 0; j < 4; j++) {
      const int n = n0 + wn + j * 16 + l15;
      const float bv = bias[n];
      for (int r = 0; r < 4; r++)
        Y[(size_t)(m + r) * DM + n] = acc[i][j][r] + bv;
    }
  }
}

extern "C" void kernel_launch(void* const* d_in, const int* in_sizes, int n_in,
                              void* d_out, int out_size, void* d_ws, size_t ws_size,
                              hipStream_t stream) {
  const float* x     = (const float*)d_in[0];
  const float* qkv_w = (const float*)d_in[1];
  const float* qkv_b = (const float*)d_in[2];
  const float* out_w = (const float*)d_in[3];
  const float* out_b = (const float*)d_in[4];
  float* out = (float*)d_out;

  const size_t NBH = (size_t)4 * 16 * SEQ * 64;   // 8,388,608 elements
  short* Q   = (short*)d_ws;
  short* K   = Q + NBH;
  short* Vt  = K + NBH;      // after attn, reused as Ob (bf16 out_w)
  short* ctx = Vt + NBH;     // before attn, holds Xb (bf16 x)
  short* Xb  = ctx;
  short* Ob  = Vt;
  short* Wb  = (short*)d_out; // bf16 qkv_w scratch in d_out (dead until out_gemm)

  cvt_bf16<<<dim3(8192), 256, 0, stream>>>(x, Xb);
  cvt_bf16<<<dim3(3072), 256, 0, stream>>>(qkv_w, Wb);
  qkv_gemm<<<dim3(64, 24), 256, 0, stream>>>(Xb, Wb, qkv_b, Q, K, Vt);
  attn<<<dim3(SEQ / 128, 64), 256, 0, stream>>>(Q, K, Vt, ctx);
  cvt_bf16<<<dim3(1024), 256, 0, stream>>>(out_w, Ob);
  out_gemm<<<dim3(64, 8), 256, 0, stream>>>(ctx, Ob, out_b, out);
}